// Round 1
// baseline (541.720 us; speedup 1.0000x reference)
//
#include <hip/hip_runtime.h>
#include <hip/hip_bf16.h>

#define B_ 2
#define H_ 4
#define HD_ 32
#define NH_ 2
#define NQ_ 2048
#define NKV_ 4096
#define DIM_ 128
#define TQ 32
#define TK 64
#define SPAN_ 257
#define SCALE_ 0.17677669529663687f
#define LAMBDA_INIT_ 0.8f

// ---------------- projection: y = x @ W + b, reshaped to [B,H,n,HD] ----------------
__global__ __launch_bounds__(128) void proj_heads(const float* __restrict__ x,
                                                  const float* __restrict__ W,
                                                  const float* __restrict__ bias,
                                                  float* __restrict__ out, int n_len) {
  int row = blockIdx.x;              // b*n_len + n
  int b = row / n_len, n = row % n_len;
  __shared__ float xr[DIM_];
  int j = threadIdx.x;
  xr[j] = x[(size_t)row * DIM_ + j];
  __syncthreads();
  float acc = bias[j];
#pragma unroll 8
  for (int i = 0; i < DIM_; ++i) acc = fmaf(xr[i], W[i * DIM_ + j], acc);
  int h = j >> 5, d = j & 31;
  out[(((size_t)b * H_ + h) * n_len + n) * HD_ + d] = acc;
}

// ---------------- final projection: out = x @ Wp + bp ----------------
__global__ __launch_bounds__(128) void proj_out(const float* __restrict__ x,
                                                const float* __restrict__ W,
                                                const float* __restrict__ bias,
                                                float* __restrict__ out) {
  int row = blockIdx.x;
  __shared__ float xr[DIM_];
  int j = threadIdx.x;
  xr[j] = x[(size_t)row * DIM_ + j];
  __syncthreads();
  float acc = bias[j];
#pragma unroll 8
  for (int i = 0; i < DIM_; ++i) acc = fmaf(xr[i], W[i * DIM_ + j], acc);
  out[(size_t)row * DIM_ + j] = acc;
}

// ---------------- fused differential flash-attention ----------------
// grid: B * NH * (NQ/TQ) blocks, 256 threads.
// block handles head pair (hp, hp+NH) for one q-tile of TQ rows.
__global__ __launch_bounds__(256) void attn_kernel(
    const float* __restrict__ Q, const float* __restrict__ K, const float* __restrict__ V,
    const int* __restrict__ cq, const int* __restrict__ ck,
    const float* __restrict__ alpha, const float* __restrict__ rpe,
    const float* __restrict__ lq1, const float* __restrict__ lk1,
    const float* __restrict__ lq2, const float* __restrict__ lk2,
    float* __restrict__ xatt) {
  const int tid = threadIdx.x;
  const int blk = blockIdx.x;
  const int qt = blk & 63;           // NQ/TQ = 64
  const int hp = (blk >> 6) & 1;     // head-pair id (NH=2)
  const int b  = blk >> 7;

  __shared__ __align__(16) float qs[2][TQ][HD_];
  __shared__ __align__(16) float ks_[2][TK][36];   // pad 36: conflict-free fp4 reads
  __shared__ __align__(16) float vs[2][TK][36];
  __shared__ float sc[2][TQ][TK + 1];              // probs, pad 65
  __shared__ int cqx[TQ], cqy[TQ];
  __shared__ int ckx[TK], cky[TK];
  __shared__ float al[TQ];
  __shared__ float mrow[2][TQ], lrow[2][TQ], frow[2][TQ];
  __shared__ float lamv;

  if (tid < TQ) {
    int qrow = qt * TQ + tid;
    cqx[tid] = cq[((size_t)b * NQ_ + qrow) * 2 + 0];
    cqy[tid] = cq[((size_t)b * NQ_ + qrow) * 2 + 1];
    al[tid]  = alpha[(size_t)b * NQ_ + qrow];
  }
  if (tid >= 64 && tid < 64 + 2 * TQ) {
    int t = tid - 64;
    mrow[t >> 5][t & 31] = -INFINITY;
    lrow[t >> 5][t & 31] = 0.f;
  }
  if (tid == 0) {
    float s1 = 0.f, s2 = 0.f;
    for (int d = 0; d < HD_; ++d) {
      s1 += lq1[hp * HD_ + d] * lk1[hp * HD_ + d];
      s2 += lq2[hp * HD_ + d] * lk2[hp * HD_ + d];
    }
    lamv = __expf(s1) - __expf(s2) + LAMBDA_INIT_;
  }
  // load q tile for both sub-heads
  for (int i = tid; i < 2 * TQ * HD_; i += 256) {
    int hh = i >> 10, r = (i >> 5) & 31, d = i & 31;
    int head = hp + hh * NH_;
    qs[hh][r][d] = Q[(((size_t)b * H_ + head) * NQ_ + qt * TQ + r) * HD_ + d];
  }
  __syncthreads();

  // score-phase thread mapping: (sub-head, q-row, k-slot)
  const int st_hp = tid >> 7;
  const int st_q  = (tid >> 2) & 31;
  const int st_ks = tid & 3;
  const int head_s = hp + st_hp * NH_;
  float4 qr[8];
#pragma unroll
  for (int j = 0; j < 8; ++j) qr[j] = *(const float4*)&qs[st_hp][st_q][j * 4];
  const int myqx = cqx[st_q], myqy = cqy[st_q];

  // PV-phase thread mapping: (q-row, 4-dim slice)
  const int pv_q = tid >> 3;
  const int pv_d = (tid & 7) * 4;

  float4 acc1 = {0, 0, 0, 0}, accx = {0, 0, 0, 0}, acc2 = {0, 0, 0, 0};

  for (int kt_i = 0; kt_i < NKV_ / TK; ++kt_i) {
    const int k0 = kt_i * TK;
    // stage K/V tiles (both sub-heads), float4-coalesced
    for (int i = tid; i < 2 * TK * 8; i += 256) {
      int hh = i >> 9, kk = (i >> 3) & 63, d4 = i & 7;
      size_t gaddr = (((size_t)b * H_ + hp + hh * NH_) * NKV_ + k0 + kk) * HD_ + d4 * 4;
      *(float4*)&ks_[hh][kk][d4 * 4] = *(const float4*)&K[gaddr];
      *(float4*)&vs[hh][kk][d4 * 4] = *(const float4*)&V[gaddr];
    }
    if (tid < TK) {
      ckx[tid] = ck[((size_t)b * NKV_ + k0 + tid) * 2 + 0];
      cky[tid] = ck[((size_t)b * NKV_ + k0 + tid) * 2 + 1];
    }
    __syncthreads();

    // ---- scores + online softmax (interleaved k: lane ks owns k = kk*4+ks) ----
    float sv[16];
    float mx = -INFINITY;
#pragma unroll
    for (int kk = 0; kk < 16; ++kk) {
      int k = kk * 4 + st_ks;
      const float4* kr = (const float4*)&ks_[st_hp][k][0];
      float dot = 0.f;
#pragma unroll
      for (int j = 0; j < 8; ++j) {
        float4 kv = kr[j];
        dot = fmaf(qr[j].x, kv.x, dot);
        dot = fmaf(qr[j].y, kv.y, dot);
        dot = fmaf(qr[j].z, kv.z, dot);
        dot = fmaf(qr[j].w, kv.w, dot);
      }
      int r0 = myqx - ckx[k] + 128; r0 = min(max(r0, 0), 256);
      int r1 = myqy - cky[k] + 128; r1 = min(max(r1, 0), 256);
      float bias_v = rpe[(size_t)(r0 * SPAN_ + r1) * H_ + head_s];
      sv[kk] = fmaf(dot, SCALE_, bias_v);
      mx = fmaxf(mx, sv[kk]);
    }
    mx = fmaxf(mx, __shfl_xor(mx, 1));
    mx = fmaxf(mx, __shfl_xor(mx, 2));
    float mold = mrow[st_hp][st_q];
    float mnew = fmaxf(mold, mx);
    float psum = 0.f;
#pragma unroll
    for (int kk = 0; kk < 16; ++kk) {
      float p = __expf(sv[kk] - mnew);
      sc[st_hp][st_q][kk * 4 + st_ks] = p;
      psum += p;
    }
    psum += __shfl_xor(psum, 1);
    psum += __shfl_xor(psum, 2);
    if (st_ks == 0) {
      float f = __expf(mold - mnew);
      frow[st_hp][st_q] = f;
      lrow[st_hp][st_q] = lrow[st_hp][st_q] * f + psum;
      mrow[st_hp][st_q] = mnew;
    }
    __syncthreads();

    // ---- PV accumulate: 3 outputs per q-row ----
    float f0 = frow[0][pv_q], f1 = frow[1][pv_q];
    acc1.x *= f0; acc1.y *= f0; acc1.z *= f0; acc1.w *= f0;
    accx.x *= f1; accx.y *= f1; accx.z *= f1; accx.w *= f1;
    acc2.x *= f1; acc2.y *= f1; acc2.z *= f1; acc2.w *= f1;
#pragma unroll 8
    for (int k = 0; k < TK; ++k) {
      float p0 = sc[0][pv_q][k];
      float p1 = sc[1][pv_q][k];
      float4 v0 = *(const float4*)&vs[0][k][pv_d];
      float4 v1 = *(const float4*)&vs[1][k][pv_d];
      acc1.x = fmaf(p0, v0.x, acc1.x); acc1.y = fmaf(p0, v0.y, acc1.y);
      acc1.z = fmaf(p0, v0.z, acc1.z); acc1.w = fmaf(p0, v0.w, acc1.w);
      accx.x = fmaf(p1, v0.x, accx.x); accx.y = fmaf(p1, v0.y, accx.y);
      accx.z = fmaf(p1, v0.z, accx.z); accx.w = fmaf(p1, v0.w, accx.w);
      acc2.x = fmaf(p1, v1.x, acc2.x); acc2.y = fmaf(p1, v1.y, acc2.y);
      acc2.z = fmaf(p1, v1.z, acc2.z); acc2.w = fmaf(p1, v1.w, acc2.w);
    }
    __syncthreads();
  }

  // ---- epilogue: combine and write x_att [B,Nq,DIM] ----
  float l0 = lrow[0][pv_q], l1 = lrow[1][pv_q];
  float a = al[pv_q], lam = lamv;
  float inv0 = 1.f / l0, inv1 = 1.f / l1;
  float4 x1, x2;
  float c1 = (1.f + a) * inv0;      // (1+a) * x_std_h
  float c2 = a * lam * inv1;        // a * lam * cross
  x1.x = c1 * acc1.x - c2 * accx.x;
  x1.y = c1 * acc1.y - c2 * accx.y;
  x1.z = c1 * acc1.z - c2 * accx.z;
  x1.w = c1 * acc1.w - c2 * accx.w;
  x2.x = acc2.x * inv1; x2.y = acc2.y * inv1;
  x2.z = acc2.z * inv1; x2.w = acc2.w * inv1;
  size_t n = (size_t)qt * TQ + pv_q;
  size_t obase = ((size_t)b * NQ_ + n) * DIM_;
  *(float4*)&xatt[obase + hp * HD_ + pv_d] = x1;
  *(float4*)&xatt[obase + (hp + NH_) * HD_ + pv_d] = x2;
}

extern "C" void kernel_launch(void* const* d_in, const int* in_sizes, int n_in,
                              void* d_out, int out_size, void* d_ws, size_t ws_size,
                              hipStream_t stream) {
  const float* x_q   = (const float*)d_in[0];
  const float* x_kv  = (const float*)d_in[1];
  const int*   cq    = (const int*)d_in[2];
  const int*   ck    = (const int*)d_in[3];
  const float* alpha = (const float*)d_in[4];
  const float* Wq    = (const float*)d_in[5];
  const float* bq    = (const float*)d_in[6];
  const float* Wk    = (const float*)d_in[7];
  const float* bk    = (const float*)d_in[8];
  const float* Wv    = (const float*)d_in[9];
  const float* bv    = (const float*)d_in[10];
  const float* lq1   = (const float*)d_in[11];
  const float* lk1   = (const float*)d_in[12];
  const float* lq2   = (const float*)d_in[13];
  const float* lk2   = (const float*)d_in[14];
  const float* rpe   = (const float*)d_in[15];
  const float* Wp    = (const float*)d_in[16];
  const float* bp    = (const float*)d_in[17];
  float* out = (float*)d_out;

  float* ws = (float*)d_ws;
  float* Qh   = ws;                       // 2*4*2048*32 = 524288
  float* Kh   = ws + 524288;              // 1048576
  float* Vh   = ws + 1572864;             // 1048576
  float* xatt = ws + 2621440;             // 524288

  proj_heads<<<dim3(B_ * NQ_), dim3(128), 0, stream>>>(x_q, Wq, bq, Qh, NQ_);
  proj_heads<<<dim3(B_ * NKV_), dim3(128), 0, stream>>>(x_kv, Wk, bk, Kh, NKV_);
  proj_heads<<<dim3(B_ * NKV_), dim3(128), 0, stream>>>(x_kv, Wv, bv, Vh, NKV_);

  attn_kernel<<<dim3(B_ * NH_ * (NQ_ / TQ)), dim3(256), 0, stream>>>(
      Qh, Kh, Vh, cq, ck, alpha, rpe, lq1, lk1, lq2, lk2, xatt);

  proj_out<<<dim3(B_ * NQ_), dim3(128), 0, stream>>>(xatt, Wp, bp, out);
}

// Round 2
// 271.433 us; speedup vs baseline: 1.9958x; 1.9958x over previous
//
#include <hip/hip_runtime.h>
#include <hip/hip_bf16.h>

#define B_ 2
#define H_ 4
#define HD_ 32
#define NH_ 2
#define NQ_ 2048
#define NKV_ 4096
#define DIM_ 128
#define SPAN_ 257
#define SCALE_ 0.17677669529663687f
#define LAMBDA_INIT_ 0.8f

typedef float f32x4 __attribute__((ext_vector_type(4)));
typedef short s16x4 __attribute__((ext_vector_type(4)));
typedef short s16x8 __attribute__((ext_vector_type(8)));
typedef int   i32x4 __attribute__((ext_vector_type(4)));
typedef float fl4   __attribute__((ext_vector_type(4)));

static __device__ __forceinline__ unsigned short f2bf(float f) {
  unsigned u = __float_as_uint(f);
  u += 0x7FFFu + ((u >> 16) & 1u);
  return (unsigned short)(u >> 16);
}

// load an 8-element bf16 fragment: elements {4g..4g+3} and {16+4g..16+4g+3}
// from a 32-element (or chunk-offset) row. Same k-map used for A and B
// operands everywhere -> exact k-assignment cancels in the MFMA.
static __device__ __forceinline__ s16x8 ldfrag(const unsigned short* base, int g) {
  s16x4 lo = *(const s16x4*)(base + 4 * g);
  s16x4 hi = *(const s16x4*)(base + 16 + 4 * g);
  s16x8 r;
  r[0] = lo[0]; r[1] = lo[1]; r[2] = lo[2]; r[3] = lo[3];
  r[4] = hi[0]; r[5] = hi[1]; r[6] = hi[2]; r[7] = hi[3];
  return r;
}

// ---------------- projections ----------------
__global__ __launch_bounds__(128) void proj_bf16(const float* __restrict__ x,
    const float* __restrict__ W, const float* __restrict__ bias,
    unsigned short* __restrict__ out, int n_len) {
  int row = blockIdx.x;
  int b = row / n_len, n = row % n_len;
  __shared__ float xr[DIM_];
  int j = threadIdx.x;
  xr[j] = x[(size_t)row * DIM_ + j];
  __syncthreads();
  float acc = bias[j];
#pragma unroll 8
  for (int i = 0; i < DIM_; ++i) acc = fmaf(xr[i], W[i * DIM_ + j], acc);
  int h = j >> 5, d = j & 31;
  out[(((size_t)b * H_ + h) * n_len + n) * HD_ + d] = f2bf(acc);
}

__global__ __launch_bounds__(128) void proj_v_t(const float* __restrict__ x,
    const float* __restrict__ W, const float* __restrict__ bias,
    unsigned short* __restrict__ out) {  // out: [B][H][HD][NKV] (transposed)
  int row = blockIdx.x;
  int b = row / NKV_, n = row % NKV_;
  __shared__ float xr[DIM_];
  int j = threadIdx.x;
  xr[j] = x[(size_t)row * DIM_ + j];
  __syncthreads();
  float acc = bias[j];
#pragma unroll 8
  for (int i = 0; i < DIM_; ++i) acc = fmaf(xr[i], W[i * DIM_ + j], acc);
  int h = j >> 5, d = j & 31;
  out[(((size_t)b * H_ + h) * HD_ + d) * NKV_ + n] = f2bf(acc);
}

__global__ __launch_bounds__(128) void proj_out(const float* __restrict__ x,
    const float* __restrict__ W, const float* __restrict__ bias,
    float* __restrict__ out) {
  int row = blockIdx.x;
  __shared__ float xr[DIM_];
  int j = threadIdx.x;
  xr[j] = x[(size_t)row * DIM_ + j];
  __syncthreads();
  float acc = bias[j];
#pragma unroll 8
  for (int i = 0; i < DIM_; ++i) acc = fmaf(xr[i], W[i * DIM_ + j], acc);
  out[(size_t)row * DIM_ + j] = acc;
}

// ---------------- MFMA differential flash-attention ----------------
// grid 512 = b(2) x hp(2) x qtile(128 of 16 rows). 4 waves: (sh 2) x (kp 2).
// Each (sh,kp) wave flash-attends its sub-head over its 2048-k half; block
// merges the two k-halves in LDS at the end.
struct StageRegs { fl4 k[4]; fl4 v[4]; int2 ck; };

__global__ __launch_bounds__(256) void attn_mfma(
    const unsigned short* __restrict__ Qg, const unsigned short* __restrict__ Kg,
    const unsigned short* __restrict__ Vg, const int* __restrict__ cq,
    const int* __restrict__ ck, const float* __restrict__ alpha,
    const float* __restrict__ rpe, const float* __restrict__ lq1,
    const float* __restrict__ lk1, const float* __restrict__ lq2,
    const float* __restrict__ lk2, float* __restrict__ xatt) {

  const int tid = threadIdx.x;
  const int lane = tid & 63;
  const int wv = tid >> 6;
  const int sh = wv >> 1;
  const int kp = wv & 1;
  const int qcol = lane & 15;
  const int g = lane >> 4;

  const int bx = blockIdx.x;
  const int qt = bx & 127;
  const int hp = (bx >> 7) & 1;
  const int b = bx >> 8;
  const int head = hp + 2 * sh;

  __shared__ __align__(16) union {
    struct {
      unsigned short Kt[2][2][64][40];   // [kp][sh][k][d pad40]
      unsigned short Vt[2][2][32][72];   // [kp][sh][d][k pad72]
      int ckx[2][64];
      int cky[2][64];
    } s;
    struct {
      float a1[2][16][33];
      float ax[2][16][33];
      float a2[2][16][33];
    } m;
  } u;
  __shared__ float mF[2][2][16], lF[2][2][16];  // [kp][sh][q]

  const int qg0 = qt * 16;
  const unsigned short* qp = Qg + (((size_t)b * H_ + head) * NQ_ + qg0 + qcol) * HD_;
  const s16x8 qf = ldfrag(qp, g);
  const int2 cqv = ((const int2*)cq)[(size_t)b * NQ_ + qg0 + qcol];

  float m_run = -INFINITY, l_run = 0.f;
  f32x4 zero4 = {0.f, 0.f, 0.f, 0.f};
  f32x4 acc1[2] = {zero4, zero4};   // sh0: P_h*V_h ; sh1: P_h2*V_h (cross)
  f32x4 acc2[2] = {zero4, zero4};   // sh1: P_h2*V_h2

  StageRegs R;
  R.ck.x = 0; R.ck.y = 0;

#define ISSUE(ST)                                                                        \
  {                                                                                      \
    const int st_ = (ST);                                                                \
    _Pragma("unroll")                                                                    \
    for (int c = 0; c < 4; ++c) {                                                        \
      int e = tid + c * 256;                                                             \
      int d4 = e & 3, kk = (e >> 2) & 63, shc = (e >> 8) & 1, kpc = e >> 9;              \
      R.k[c] = *(const fl4*)(Kg + (((size_t)b * H_ + hp + 2 * shc) * NKV_ +              \
                 (size_t)kpc * 2048 + st_ * 64 + kk) * HD_ + d4 * 8);                    \
      int kg8 = e & 7, dv = (e >> 3) & 31;                                               \
      R.v[c] = *(const fl4*)(Vg + (((size_t)b * H_ + hp + 2 * shc) * HD_ + dv) * NKV_ +  \
                 (size_t)kpc * 2048 + st_ * 64 + kg8 * 8);                               \
    }                                                                                    \
    if (tid < 128)                                                                       \
      R.ck = ((const int2*)ck)[(size_t)b * NKV_ + (size_t)(tid >> 6) * 2048 +            \
                               st_ * 64 + (tid & 63)];                                   \
  }

  ISSUE(0);

  for (int st = 0; st < 32; ++st) {
    __syncthreads();  // previous tile fully consumed
#pragma unroll
    for (int c = 0; c < 4; ++c) {
      int e = tid + c * 256;
      int d4 = e & 3, kk = (e >> 2) & 63, shc = (e >> 8) & 1, kpc = e >> 9;
      *(fl4*)&u.s.Kt[kpc][shc][kk][d4 * 8] = R.k[c];
      int kg8 = e & 7, dv = (e >> 3) & 31;
      *(fl4*)&u.s.Vt[kpc][shc][dv][kg8 * 8] = R.v[c];
    }
    if (tid < 128) {
      u.s.ckx[tid >> 6][tid & 63] = R.ck.x;
      u.s.cky[tid >> 6][tid & 63] = R.ck.y;
    }
    __syncthreads();
    if (st + 1 < 32) ISSUE(st + 1);

    // ---- bias gathers (issued early; overlap with MFMAs) ----
    float bias[16];
#pragma unroll
    for (int t = 0; t < 4; ++t) {
      i32x4 kx = *(const i32x4*)&u.s.ckx[kp][16 * t + 4 * g];
      i32x4 ky = *(const i32x4*)&u.s.cky[kp][16 * t + 4 * g];
#pragma unroll
      for (int r = 0; r < 4; ++r) {
        int dx = cqv.x - kx[r] + 128; dx = dx < 0 ? 0 : (dx > 256 ? 256 : dx);
        int dy = cqv.y - ky[r] + 128; dy = dy < 0 ? 0 : (dy > 256 ? 256 : dy);
        bias[t * 4 + r] = rpe[(size_t)(dx * SPAN_ + dy) * H_ + head];
      }
    }

    // ---- S^T = K * Q^T : 4 MFMAs (64k x 16q), lane holds q=qcol, k=16t+4g+r
    f32x4 s4[4];
#pragma unroll
    for (int t = 0; t < 4; ++t) {
      s16x8 kf = ldfrag(&u.s.Kt[kp][sh][16 * t + qcol][0], g);
      s4[t] = __builtin_amdgcn_mfma_f32_16x16x32_bf16(kf, qf, zero4, 0, 0, 0);
    }

    // ---- online softmax (lane-local + 2 shfl over the 4 g-groups) ----
    float sv[16], mx = -INFINITY;
#pragma unroll
    for (int i = 0; i < 16; ++i) {
      sv[i] = fmaf(s4[i >> 2][i & 3], SCALE_, bias[i]);
      mx = fmaxf(mx, sv[i]);
    }
    mx = fmaxf(mx, __shfl_xor(mx, 16));
    mx = fmaxf(mx, __shfl_xor(mx, 32));
    float mnew = fmaxf(m_run, mx);
    float fold = __expf(m_run - mnew);
    float p[16], ps = 0.f;
#pragma unroll
    for (int i = 0; i < 16; ++i) { p[i] = __expf(sv[i] - mnew); ps += p[i]; }
    ps += __shfl_xor(ps, 16);
    ps += __shfl_xor(ps, 32);
    l_run = l_run * fold + ps;
    m_run = mnew;

    // rescale accumulators: acc row q = 4g + r -> fetch fold for that q
    int gb = 4 * g;
    float fr0 = __shfl(fold, gb + 0), fr1 = __shfl(fold, gb + 1);
    float fr2 = __shfl(fold, gb + 2), fr3 = __shfl(fold, gb + 3);
#pragma unroll
    for (int dt = 0; dt < 2; ++dt) {
      acc1[dt][0] *= fr0; acc1[dt][1] *= fr1; acc1[dt][2] *= fr2; acc1[dt][3] *= fr3;
    }
    if (sh == 1) {
#pragma unroll
      for (int dt = 0; dt < 2; ++dt) {
        acc2[dt][0] *= fr0; acc2[dt][1] *= fr1; acc2[dt][2] *= fr2; acc2[dt][3] *= fr3;
      }
    }

    // pack P -> bf16 A-fragments (k-map matches ldfrag's f(g,j))
    s16x8 pa[2];
#pragma unroll
    for (int c = 0; c < 2; ++c)
#pragma unroll
      for (int j = 0; j < 8; ++j) pa[c][j] = (short)f2bf(p[8 * c + j]);

    // ---- PV ----
#pragma unroll
    for (int c = 0; c < 2; ++c) {
#pragma unroll
      for (int dt = 0; dt < 2; ++dt) {
        s16x8 vf0 = ldfrag(&u.s.Vt[kp][0][dt * 16 + qcol][32 * c], g);
        acc1[dt] = __builtin_amdgcn_mfma_f32_16x16x32_bf16(pa[c], vf0, acc1[dt], 0, 0, 0);
        if (sh == 1) {
          s16x8 vf1 = ldfrag(&u.s.Vt[kp][1][dt * 16 + qcol][32 * c], g);
          acc2[dt] = __builtin_amdgcn_mfma_f32_16x16x32_bf16(pa[c], vf1, acc2[dt], 0, 0, 0);
        }
      }
    }
  }

  // ---- merge the two k-halves + epilogue ----
  if (lane < 16) { mF[kp][sh][lane] = m_run; lF[kp][sh][lane] = l_run; }
  __syncthreads();  // all staging reads done; safe to overwrite union

#pragma unroll
  for (int dt = 0; dt < 2; ++dt)
#pragma unroll
    for (int r = 0; r < 4; ++r) {
      int q = 4 * g + r, d = dt * 16 + qcol;
      if (sh == 0) u.m.a1[kp][q][d] = acc1[dt][r];
      else { u.m.ax[kp][q][d] = acc1[dt][r]; u.m.a2[kp][q][d] = acc2[dt][r]; }
    }
  __syncthreads();

  {
    int q = tid >> 4, dp = (tid & 15) * 2;
    int qg = qg0 + q;
    float m00 = mF[0][0][q], m01 = mF[1][0][q];
    float M0 = fmaxf(m00, m01);
    float w00 = __expf(m00 - M0), w01 = __expf(m01 - M0);
    float L0 = lF[0][0][q] * w00 + lF[1][0][q] * w01;
    float m10 = mF[0][1][q], m11 = mF[1][1][q];
    float M1 = fmaxf(m10, m11);
    float w10 = __expf(m10 - M1), w11 = __expf(m11 - M1);
    float L1 = lF[0][1][q] * w10 + lF[1][1][q] * w11;
    float s1 = 0.f, s2 = 0.f;
#pragma unroll
    for (int d0 = 0; d0 < HD_; ++d0) {
      s1 += lq1[hp * HD_ + d0] * lk1[hp * HD_ + d0];
      s2 += lq2[hp * HD_ + d0] * lk2[hp * HD_ + d0];
    }
    float lam = __expf(s1) - __expf(s2) + LAMBDA_INIT_;
    float a = alpha[(size_t)b * NQ_ + qg];
    float i0 = 1.f / L0, i1 = 1.f / L1;
    size_t ob = ((size_t)b * NQ_ + qg) * DIM_;
#pragma unroll
    for (int e = 0; e < 2; ++e) {
      int d = dp + e;
      float A1 = u.m.a1[0][q][d] * w00 + u.m.a1[1][q][d] * w01;
      float AX = u.m.ax[0][q][d] * w10 + u.m.ax[1][q][d] * w11;
      float A2 = u.m.a2[0][q][d] * w10 + u.m.a2[1][q][d] * w11;
      xatt[ob + hp * HD_ + d] = (1.f + a) * A1 * i0 - a * lam * AX * i1;
      xatt[ob + hp * HD_ + 64 + d] = A2 * i1;
    }
  }
}

extern "C" void kernel_launch(void* const* d_in, const int* in_sizes, int n_in,
                              void* d_out, int out_size, void* d_ws, size_t ws_size,
                              hipStream_t stream) {
  const float* x_q   = (const float*)d_in[0];
  const float* x_kv  = (const float*)d_in[1];
  const int*   cq    = (const int*)d_in[2];
  const int*   ckc   = (const int*)d_in[3];
  const float* alpha = (const float*)d_in[4];
  const float* Wq    = (const float*)d_in[5];
  const float* bq    = (const float*)d_in[6];
  const float* Wk    = (const float*)d_in[7];
  const float* bk    = (const float*)d_in[8];
  const float* Wv    = (const float*)d_in[9];
  const float* bv    = (const float*)d_in[10];
  const float* lq1   = (const float*)d_in[11];
  const float* lk1   = (const float*)d_in[12];
  const float* lq2   = (const float*)d_in[13];
  const float* lk2   = (const float*)d_in[14];
  const float* rpe   = (const float*)d_in[15];
  const float* Wp    = (const float*)d_in[16];
  const float* bp    = (const float*)d_in[17];
  float* out = (float*)d_out;

  char* w = (char*)d_ws;
  unsigned short* Qb  = (unsigned short*)w;                    // 1 MB
  unsigned short* Kb  = (unsigned short*)(w + 1048576);        // 2 MB
  unsigned short* Vtb = (unsigned short*)(w + 3145728);        // 2 MB
  float*          xat = (float*)(w + 5242880);                 // 2 MB

  proj_bf16<<<dim3(B_ * NQ_), dim3(128), 0, stream>>>(x_q, Wq, bq, Qb, NQ_);
  proj_bf16<<<dim3(B_ * NKV_), dim3(128), 0, stream>>>(x_kv, Wk, bk, Kb, NKV_);
  proj_v_t<<<dim3(B_ * NKV_), dim3(128), 0, stream>>>(x_kv, Wv, bv, Vtb);

  attn_mfma<<<dim3(512), dim3(256), 0, stream>>>(Qb, Kb, Vtb, cq, ckc, alpha,
                                                 rpe, lq1, lk1, lq2, lk2, xat);

  proj_out<<<dim3(B_ * NQ_), dim3(128), 0, stream>>>(xat, Wp, bp, out);
}

// Round 3
// 136.016 us; speedup vs baseline: 3.9828x; 1.9956x over previous
//
#include <hip/hip_runtime.h>
#include <hip/hip_bf16.h>

#define B_ 2
#define H_ 4
#define HD_ 32
#define NQ_ 2048
#define NKV_ 4096
#define DIM_ 128
#define SPAN_ 257
#define SCALE_ 0.17677669529663687f
#define LAMBDA_INIT_ 0.8f
#define KT 32
#define NT 64

typedef float f32x4 __attribute__((ext_vector_type(4)));
typedef short s16x4 __attribute__((ext_vector_type(4)));
typedef short s16x8 __attribute__((ext_vector_type(8)));
typedef float fl4   __attribute__((ext_vector_type(4)));

static __device__ __forceinline__ unsigned short f2bf(float f) {
  unsigned u = __float_as_uint(f);
  u += 0x7FFFu + ((u >> 16) & 1u);
  return (unsigned short)(u >> 16);
}

// V-fragment: cols {4g..4g+3} and {16+4g..16+4g+3} of a 32-wide row
static __device__ __forceinline__ s16x8 ldfragV(const unsigned short* base, int g) {
  s16x4 lo = *(const s16x4*)(base + 4 * g);
  s16x4 hi = *(const s16x4*)(base + 16 + 4 * g);
  s16x8 r;
  r[0] = lo[0]; r[1] = lo[1]; r[2] = lo[2]; r[3] = lo[3];
  r[4] = hi[0]; r[5] = hi[1]; r[6] = hi[2]; r[7] = hi[3];
  return r;
}

// ---------------- 8-row-blocked projections (W read amortized 8x) ----------------
__global__ __launch_bounds__(128) void proj_bf16(const float* __restrict__ x,
    const float* __restrict__ W, const float* __restrict__ bias,
    unsigned short* __restrict__ out, int n_len) {
  int row0 = blockIdx.x * 8;
  int b = row0 / n_len, n0 = row0 % n_len;
  __shared__ float xr[8][DIM_ + 1];
  int j = threadIdx.x;
#pragma unroll
  for (int r = 0; r < 8; ++r) xr[r][j] = x[(size_t)(row0 + r) * DIM_ + j];
  __syncthreads();
  float acc[8];
  float bb = bias[j];
#pragma unroll
  for (int r = 0; r < 8; ++r) acc[r] = bb;
#pragma unroll 4
  for (int i = 0; i < DIM_; ++i) {
    float w = W[i * DIM_ + j];
#pragma unroll
    for (int r = 0; r < 8; ++r) acc[r] = fmaf(xr[r][i], w, acc[r]);
  }
  int h = j >> 5, d = j & 31;
#pragma unroll
  for (int r = 0; r < 8; ++r)
    out[(((size_t)b * H_ + h) * n_len + n0 + r) * HD_ + d] = f2bf(acc[r]);
}

__global__ __launch_bounds__(128) void proj_v_t(const float* __restrict__ x,
    const float* __restrict__ W, const float* __restrict__ bias,
    unsigned short* __restrict__ out) {  // out: [B][H][HD][NKV]
  int row0 = blockIdx.x * 8;
  int b = row0 / NKV_, n0 = row0 % NKV_;
  __shared__ float xr[8][DIM_ + 1];
  int j = threadIdx.x;
#pragma unroll
  for (int r = 0; r < 8; ++r) xr[r][j] = x[(size_t)(row0 + r) * DIM_ + j];
  __syncthreads();
  float acc[8];
  float bb = bias[j];
#pragma unroll
  for (int r = 0; r < 8; ++r) acc[r] = bb;
#pragma unroll 4
  for (int i = 0; i < DIM_; ++i) {
    float w = W[i * DIM_ + j];
#pragma unroll
    for (int r = 0; r < 8; ++r) acc[r] = fmaf(xr[r][i], w, acc[r]);
  }
  int h = j >> 5, d = j & 31;
  s16x8 t8;
#pragma unroll
  for (int r = 0; r < 8; ++r) t8[r] = (short)f2bf(acc[r]);
  *(s16x8*)(out + (((size_t)b * H_ + h) * HD_ + d) * NKV_ + n0) = t8;
}

__global__ __launch_bounds__(128) void proj_out(const float* __restrict__ x,
    const float* __restrict__ W, const float* __restrict__ bias,
    float* __restrict__ out) {
  int row0 = blockIdx.x * 8;
  __shared__ float xr[8][DIM_ + 1];
  int j = threadIdx.x;
#pragma unroll
  for (int r = 0; r < 8; ++r) xr[r][j] = x[(size_t)(row0 + r) * DIM_ + j];
  __syncthreads();
  float acc[8];
  float bb = bias[j];
#pragma unroll
  for (int r = 0; r < 8; ++r) acc[r] = bb;
#pragma unroll 4
  for (int i = 0; i < DIM_; ++i) {
    float w = W[i * DIM_ + j];
#pragma unroll
    for (int r = 0; r < 8; ++r) acc[r] = fmaf(xr[r][i], w, acc[r]);
  }
#pragma unroll
  for (int r = 0; r < 8; ++r) out[(size_t)(row0 + r) * DIM_ + j] = acc[r];
}

// ---------------- 4-head differential flash-attention ----------------
// grid 256 = b(2) x qtile(128 of 16 rows). 512 thr = 8 waves: (kp 2) x (h 4).
// One float4 rpe gather per (q,k) serves all 4 heads via LDS bias tile.
// K never touches LDS: direct global->register MFMA fragments.
struct KVR { s16x8 kf[2]; fl4 v[2]; };

__global__ __launch_bounds__(512) void attn4(
    const unsigned short* __restrict__ Qg, const unsigned short* __restrict__ Kg,
    const unsigned short* __restrict__ Vg, const int* __restrict__ cq,
    const int* __restrict__ ck, const float* __restrict__ alpha,
    const float* __restrict__ rpe, const float* __restrict__ lq1,
    const float* __restrict__ lk1, const float* __restrict__ lq2,
    const float* __restrict__ lk2, float* __restrict__ xatt) {

  const int tid = threadIdx.x;
  const int lane = tid & 63;
  const int wv = tid >> 6;       // 0..7
  const int h = wv & 3;          // head
  const int kp = wv >> 2;        // k-half
  const int qcol = lane & 15;
  const int g = lane >> 4;

  const int qt = blockIdx.x & 127;
  const int b = blockIdx.x >> 7;
  const int qg0 = qt * 16;

  __shared__ __align__(16) union {
    struct {
      unsigned short Vt[2][4][32][40];  // [kp][h][d][k pad40]
      float bias[2][4][16][40];         // [kp][h][q][k pad40]
    } s;
    struct {
      float aS[2][4][16][33];
      float aC[2][2][16][33];
    } m;
  } u;
  __shared__ float mF[2][4][16], lF[2][4][16];
  __shared__ float lamS[2];

  if (tid < 2) {
    float s1 = 0.f, s2 = 0.f;
    for (int d = 0; d < HD_; ++d) {
      s1 += lq1[tid * HD_ + d] * lk1[tid * HD_ + d];
      s2 += lq2[tid * HD_ + d] * lk2[tid * HD_ + d];
    }
    lamS[tid] = __expf(s1) - __expf(s2) + LAMBDA_INIT_;
  }

  // Q fragment (k-map 8g+j, matching K's direct-load map)
  const s16x8 qf = *(const s16x8*)(Qg +
      (((size_t)b * H_ + h) * NQ_ + qg0 + qcol) * HD_ + 8 * g);

  // gather-duty constants: this thread owns (gkp, gk) column, q rows 2*wv+c
  const int gk = lane & 31;
  const int gkp = lane >> 5;
  int2 cqg[2];
#pragma unroll
  for (int c = 0; c < 2; ++c)
    cqg[c] = ((const int2*)cq)[(size_t)b * NQ_ + qg0 + 2 * wv + c];
  const int2* ckp = (const int2*)ck + (size_t)b * NKV_ + gkp * 2048 + gk;

  // V-stage lane constants (e = tid + 512c)
  int v_k16[2], v_d[2], v_h[2], v_kp[2];
  const unsigned short* v_src[2];
#pragma unroll
  for (int c = 0; c < 2; ++c) {
    int e = tid + 512 * c;
    v_k16[c] = e & 3; v_d[c] = (e >> 2) & 31; v_h[c] = (e >> 7) & 3; v_kp[c] = (e >> 9) & 1;
    v_src[c] = Vg + (((size_t)b * H_ + v_h[c]) * HD_ + v_d[c]) * NKV_ +
               v_kp[c] * 2048 + v_k16[c] * 8;
  }
  // K lane constants
  const unsigned short* kbase = Kg + (((size_t)b * H_ + h) * NKV_ + kp * 2048) * HD_;
  int koff[2];
#pragma unroll
  for (int t = 0; t < 2; ++t) koff[t] = (16 * t + qcol) * HD_ + 8 * g;

  const fl4* rpe4 = (const fl4*)rpe;

  float m_run = -INFINITY, l_run = 0.f;
  f32x4 zero4 = {0.f, 0.f, 0.f, 0.f};
  f32x4 acc1[2] = {zero4, zero4};
  f32x4 acc2[2] = {zero4, zero4};

#define LOADKV(DST, ST)                                                     \
  {                                                                         \
    const int s_ = (ST);                                                    \
    DST.kf[0] = *(const s16x8*)(kbase + s_ * KT * HD_ + koff[0]);           \
    DST.kf[1] = *(const s16x8*)(kbase + s_ * KT * HD_ + koff[1]);           \
    DST.v[0] = *(const fl4*)(v_src[0] + s_ * KT);                           \
    DST.v[1] = *(const fl4*)(v_src[1] + s_ * KT);                           \
  }
#define GATHER(GD, CKV)                                                     \
  {                                                                         \
    _Pragma("unroll")                                                       \
    for (int c = 0; c < 2; ++c) {                                           \
      int dx = cqg[c].x - (CKV).x + 128; dx = dx < 0 ? 0 : (dx > 256 ? 256 : dx); \
      int dy = cqg[c].y - (CKV).y + 128; dy = dy < 0 ? 0 : (dy > 256 ? 256 : dy); \
      GD[c] = rpe4[dx * SPAN_ + dy];                                        \
    }                                                                       \
  }

  KVR kv, kv2;
  fl4 gR[2];
  int2 ckR = ckp[0];
  LOADKV(kv, 0);
  GATHER(gR, ckR);          // tile 0
  ckR = ckp[KT];            // tile 1 coords

  for (int st = 0; st < NT; ++st) {
    __syncthreads();  // previous tile fully consumed
    // stage V + bias from registers
#pragma unroll
    for (int c = 0; c < 2; ++c)
      *(fl4*)&u.s.Vt[v_kp[c]][v_h[c]][v_d[c]][v_k16[c] * 8] = kv.v[c];
#pragma unroll
    for (int c = 0; c < 2; ++c) {
      int qq = 2 * wv + c;
      u.s.bias[gkp][0][qq][gk] = gR[c][0];
      u.s.bias[gkp][1][qq][gk] = gR[c][1];
      u.s.bias[gkp][2][qq][gk] = gR[c][2];
      u.s.bias[gkp][3][qq][gk] = gR[c][3];
    }
    int stn = st + 1 < NT ? st + 1 : NT - 1;
    LOADKV(kv2, stn);
    __syncthreads();
    GATHER(gR, ckR);                       // tile st+1
    ckR = ckp[(st + 2 < NT ? st + 2 : NT - 1) * KT];

    // ---- compute tile st ----
    fl4 bs0 = *(const fl4*)&u.s.bias[kp][h][qcol][4 * g];
    fl4 bs1 = *(const fl4*)&u.s.bias[kp][h][qcol][16 + 4 * g];
    f32x4 sA = __builtin_amdgcn_mfma_f32_16x16x32_bf16(kv.kf[0], qf, zero4, 0, 0, 0);
    f32x4 sB = __builtin_amdgcn_mfma_f32_16x16x32_bf16(kv.kf[1], qf, zero4, 0, 0, 0);
    float sv0[4], sv1[4], mx = -INFINITY;
#pragma unroll
    for (int r = 0; r < 4; ++r) {
      sv0[r] = fmaf(sA[r], SCALE_, bs0[r]);
      sv1[r] = fmaf(sB[r], SCALE_, bs1[r]);
      mx = fmaxf(mx, fmaxf(sv0[r], sv1[r]));
    }
    mx = fmaxf(mx, __shfl_xor(mx, 16));
    mx = fmaxf(mx, __shfl_xor(mx, 32));
    float mnew = fmaxf(m_run, mx);
    float fold = __expf(m_run - mnew);
    float p0[4], p1[4], ps = 0.f;
#pragma unroll
    for (int r = 0; r < 4; ++r) {
      p0[r] = __expf(sv0[r] - mnew);
      p1[r] = __expf(sv1[r] - mnew);
      ps += p0[r] + p1[r];
    }
    ps += __shfl_xor(ps, 16);
    ps += __shfl_xor(ps, 32);
    l_run = l_run * fold + ps;
    m_run = mnew;
    float fr[4];
#pragma unroll
    for (int r = 0; r < 4; ++r) fr[r] = __shfl(fold, 4 * g + r);
#pragma unroll
    for (int dt = 0; dt < 2; ++dt)
#pragma unroll
      for (int r = 0; r < 4; ++r) acc1[dt][r] *= fr[r];
    if (h >= 2) {
#pragma unroll
      for (int dt = 0; dt < 2; ++dt)
#pragma unroll
        for (int r = 0; r < 4; ++r) acc2[dt][r] *= fr[r];
    }
    s16x8 pa;
#pragma unroll
    for (int r = 0; r < 4; ++r) {
      pa[r] = (short)f2bf(p0[r]);
      pa[r + 4] = (short)f2bf(p1[r]);
    }
#pragma unroll
    for (int dt = 0; dt < 2; ++dt) {
      s16x8 vf = ldfragV(&u.s.Vt[kp][h][dt * 16 + qcol][0], g);
      acc1[dt] = __builtin_amdgcn_mfma_f32_16x16x32_bf16(pa, vf, acc1[dt], 0, 0, 0);
    }
    if (h >= 2) {
#pragma unroll
      for (int dt = 0; dt < 2; ++dt) {
        s16x8 vf = ldfragV(&u.s.Vt[kp][h - 2][dt * 16 + qcol][0], g);
        acc2[dt] = __builtin_amdgcn_mfma_f32_16x16x32_bf16(pa, vf, acc2[dt], 0, 0, 0);
      }
    }
    kv = kv2;
  }

  // ---- epilogue: merge k-halves, combine heads ----
  if (lane < 16) { mF[kp][h][lane] = m_run; lF[kp][h][lane] = l_run; }
  __syncthreads();  // all compute done; safe to overwrite union
#pragma unroll
  for (int dt = 0; dt < 2; ++dt)
#pragma unroll
    for (int r = 0; r < 4; ++r) {
      int q = 4 * g + r, d = dt * 16 + qcol;
      u.m.aS[kp][h][q][d] = acc1[dt][r];
      if (h >= 2) u.m.aC[kp][h - 2][q][d] = acc2[dt][r];
    }
  __syncthreads();

  {
    int q = tid >> 5, j = tid & 31;
    int qg = qg0 + q;
    float W0[4], W1[4], Ls[4], As[4];
#pragma unroll
    for (int hh = 0; hh < 4; ++hh) {
      float m0 = mF[0][hh][q], m1 = mF[1][hh][q];
      float M = fmaxf(m0, m1);
      float w0 = __expf(m0 - M), w1 = __expf(m1 - M);
      W0[hh] = w0; W1[hh] = w1;
      Ls[hh] = lF[0][hh][q] * w0 + lF[1][hh][q] * w1;
      As[hh] = u.m.aS[0][hh][q][j] * w0 + u.m.aS[1][hh][q][j] * w1;
    }
    float a = alpha[(size_t)b * NQ_ + qg];
    size_t ob = ((size_t)b * NQ_ + qg) * DIM_;
#pragma unroll
    for (int hp = 0; hp < 2; ++hp) {
      float AX = u.m.aC[0][hp][q][j] * W0[hp + 2] + u.m.aC[1][hp][q][j] * W1[hp + 2];
      float i0 = 1.f / Ls[hp], i1 = 1.f / Ls[hp + 2];
      xatt[ob + hp * HD_ + j] = (1.f + a) * As[hp] * i0 - a * lamS[hp] * AX * i1;
      xatt[ob + (hp + 2) * HD_ + j] = As[hp + 2] * i1;
    }
  }
}

extern "C" void kernel_launch(void* const* d_in, const int* in_sizes, int n_in,
                              void* d_out, int out_size, void* d_ws, size_t ws_size,
                              hipStream_t stream) {
  const float* x_q   = (const float*)d_in[0];
  const float* x_kv  = (const float*)d_in[1];
  const int*   cq    = (const int*)d_in[2];
  const int*   ckc   = (const int*)d_in[3];
  const float* alpha = (const float*)d_in[4];
  const float* Wq    = (const float*)d_in[5];
  const float* bq    = (const float*)d_in[6];
  const float* Wk    = (const float*)d_in[7];
  const float* bk    = (const float*)d_in[8];
  const float* Wv    = (const float*)d_in[9];
  const float* bv    = (const float*)d_in[10];
  const float* lq1   = (const float*)d_in[11];
  const float* lk1   = (const float*)d_in[12];
  const float* lq2   = (const float*)d_in[13];
  const float* lk2   = (const float*)d_in[14];
  const float* rpe   = (const float*)d_in[15];
  const float* Wp    = (const float*)d_in[16];
  const float* bp    = (const float*)d_in[17];
  float* out = (float*)d_out;

  char* w = (char*)d_ws;
  unsigned short* Qb  = (unsigned short*)w;                    // 1 MB
  unsigned short* Kb  = (unsigned short*)(w + 1048576);        // 2 MB
  unsigned short* Vtb = (unsigned short*)(w + 3145728);        // 2 MB
  float*          xat = (float*)(w + 5242880);                 // 2 MB

  proj_bf16<<<dim3(B_ * NQ_ / 8), dim3(128), 0, stream>>>(x_q, Wq, bq, Qb, NQ_);
  proj_bf16<<<dim3(B_ * NKV_ / 8), dim3(128), 0, stream>>>(x_kv, Wk, bk, Kb, NKV_);
  proj_v_t<<<dim3(B_ * NKV_ / 8), dim3(128), 0, stream>>>(x_kv, Wv, bv, Vtb);

  attn4<<<dim3(B_ * (NQ_ / 16)), dim3(512), 0, stream>>>(
      Qb, Kb, Vtb, cq, ckc, alpha, rpe, lq1, lk1, lq2, lk2, xat);

  proj_out<<<dim3(B_ * NQ_ / 8), dim3(128), 0, stream>>>(xat, Wp, bp, out);
}